// Round 1
// baseline (1175.959 us; speedup 1.0000x reference)
//
#include <hip/hip_runtime.h>

typedef unsigned short u16;
typedef unsigned int u32;
typedef __attribute__((ext_vector_type(8))) short short8;
typedef __attribute__((ext_vector_type(4))) float f32x4;
typedef __attribute__((ext_vector_type(4))) u16 ushort4_t;

// ---------- scalar conversion helpers --------------------------------------
__device__ __forceinline__ float bf2f(u16 u) {
    u32 x = ((u32)u) << 16;
    return __uint_as_float(x);
}
__device__ __forceinline__ u16 f2bf(float f) {  // round-to-nearest-even
    u32 x = __float_as_uint(f);
    x += 0x7FFFu + ((x >> 16) & 1u);
    return (u16)(x >> 16);
}
// packed f32x2 -> bf16x2 (RNE), gfx950 HW instruction
__device__ __forceinline__ u32 cvtpk_bf16(float lo, float hi) {
    u32 r;
    asm("v_cvt_pk_bf16_f32 %0, %1, %2" : "=v"(r) : "v"(lo), "v"(hi));
    return r;
}
// 2^x via HW transcendental (no libm guard code)
__device__ __forceinline__ float exp2_hw(float x) {
    float r;
    asm("v_exp_f32 %0, %1" : "=v"(r) : "v"(x));
    return r;
}

// ---------- async global->LDS (16B per lane, wave-uniform base) ------------
using as1_cv = __attribute__((address_space(1))) const void;
using as3_v  = __attribute__((address_space(3))) void;
__device__ __forceinline__ void gld16(const void* g, void* l) {
    __builtin_amdgcn_global_load_lds((as1_cv*)g, (as3_v*)l, 16, 0, 0);
}

// ---------- fp32 -> bf16 convert (4 elems/thread) --------------------------
__global__ void cvt_f32_bf16(const float* __restrict__ in, u16* __restrict__ out, int n4) {
    int i = blockIdx.x * 256 + threadIdx.x;
    if (i >= n4) return;
    float4 v = ((const float4*)in)[i];
    ushort4_t o;
    o[0] = f2bf(v.x); o[1] = f2bf(v.y); o[2] = f2bf(v.z); o[3] = f2bf(v.w);
    ((ushort4_t*)out)[i] = o;
}

// ---------- GEMM: C[M,N] = A[M,K] * B[N,K]^T, bf16 inputs ------------------
// OUT_MODE: 0 = bf16 out, 1 = f32 out, 3 = bf16 TRANSPOSED out (Ct[N,M])
template <int OUT_MODE>
__global__ __launch_bounds__(256) void gemm_bt(
    const u16* __restrict__ A, const u16* __restrict__ B,
    u16* __restrict__ Cb, float* __restrict__ Cf,
    int M, int N, int K)
{
    __shared__ __align__(16) u16 As[128 * 32];
    __shared__ __align__(16) u16 Bs[128 * 32];
    const int t    = threadIdx.x;
    const int lane = t & 63;
    const int w    = t >> 6;
    const int wm   = w & 1;
    const int wn   = w >> 1;
    const int bx   = blockIdx.x;   // N tile
    const int by   = blockIdx.y;   // M tile

    const int r  = t >> 2;
    const int c8 = (t & 3) * 8;
    const u16* gA0 = A + (size_t)(by * 128 + r) * K + c8;
    const u16* gA1 = gA0 + (size_t)64 * K;
    const u16* gB0 = B + (size_t)(bx * 128 + r) * K + c8;
    const u16* gB1 = gB0 + (size_t)64 * K;
    u16* lA0 = &As[t * 8];
    u16* lA1 = &As[2048 + t * 8];
    u16* lB0 = &Bs[t * 8];
    u16* lB1 = &Bs[2048 + t * 8];

    f32x4 acc[4][4] = {};

    const int arow = wm * 64 + (lane & 15);
    const int brow = wn * 64 + (lane & 15);
    const int koff = (lane >> 4) * 8;

    for (int kt = 0; kt < K; kt += 32) {
        gld16(gA0 + kt, lA0);
        gld16(gA1 + kt, lA1);
        gld16(gB0 + kt, lB0);
        gld16(gB1 + kt, lB1);
        __syncthreads();
        short8 af[4], bf[4];
#pragma unroll
        for (int i = 0; i < 4; i++)
            af[i] = *(const short8*)&As[(arow + i * 16) * 32 + koff];
#pragma unroll
        for (int i = 0; i < 4; i++)
            bf[i] = *(const short8*)&Bs[(brow + i * 16) * 32 + koff];
#pragma unroll
        for (int mi = 0; mi < 4; mi++)
#pragma unroll
            for (int ni = 0; ni < 4; ni++)
                acc[mi][ni] = __builtin_amdgcn_mfma_f32_16x16x32_bf16(
                    af[mi], bf[ni], acc[mi][ni], 0, 0, 0);
        __syncthreads();
    }

    const int row0 = by * 128 + wm * 64 + (lane >> 4) * 4;
    const int col0 = bx * 128 + wn * 64 + (lane & 15);
#pragma unroll
    for (int mi = 0; mi < 4; mi++) {
#pragma unroll
        for (int ni = 0; ni < 4; ni++) {
            if (OUT_MODE == 3) {
                // transposed bf16: Ct[col][row], 4 consecutive rows -> 8B store
                ushort4_t o;
#pragma unroll
                for (int rr = 0; rr < 4; rr++) o[rr] = f2bf(acc[mi][ni][rr]);
                int col = col0 + ni * 16;
                *(ushort4_t*)&Cb[(size_t)col * M + row0 + mi * 16] = o;
            } else {
#pragma unroll
                for (int rr = 0; rr < 4; rr++) {
                    int row = row0 + mi * 16 + rr;
                    int col = col0 + ni * 16;
                    float v = acc[mi][ni][rr];
                    if (OUT_MODE == 1) Cf[(size_t)row * N + col] = v;
                    else               Cb[(size_t)row * N + col] = f2bf(v);
                }
            }
        }
    }
}

// ---------- RoPE in-place on bf16 [B*S, H*128] -----------------------------
__global__ void rope_k(u16* __restrict__ x, int hshift) {
    int idx = blockIdx.x * 256 + threadIdx.x;
    int i   = idx & 63;
    int hm  = (1 << (hshift - 6)) - 1;
    int h   = (idx >> 6) & hm;
    int row = idx >> hshift;       // 0..B*S-1
    int s   = row & 2047;          // position within sequence
    int stride = (hm + 1) * 128;
    size_t base = (size_t)row * stride + h * 128 + i;
    float th = (float)s * powf(10000.0f, -(float)i / 64.0f);
    float cs = cosf(th), sn = sinf(th);
    float x1 = bf2f(x[base]), x2 = bf2f(x[base + 64]);
    x[base]      = f2bf(x1 * cs - x2 * sn);
    x[base + 64] = f2bf(x2 * cs + x1 * sn);
}

// ---------- causal flash attention -----------------------------------------
// grid (16, NH, B); 256 thr = 4 waves; block = 128 q rows; wave = 32 q rows
// (2 subtiles of 16 sharing K/V fragments). KVBLK = 64 keys/step,
// double-buffered LDS (prefetch next tile while computing current -> one
// __syncthreads per 64 keys).
// scores: S^T = Kperm * Q^T  (A rows permuted: key(m) = (m>>2)*8+kk*4+(m&3))
//   -> C rows land exactly in PV B-operand key order g*8+j.
// PV: O^T += V^T * P^T, V^T staged [dim][64key] with per-row XOR swizzle
//   cc ^= (dim&7) so 16-lane col groups cover 8 distinct bank pairs (2-way,
//   free) instead of the previous 8-way conflict.
// Softmax: log2 domain (v_exp_f32 direct), one reduce per 64 keys, deferred
// rescale (THR=8: skip O-rescale unless tile max exceeds running max by >8).
__global__ __launch_bounds__(256) void flash_attn(
    const u16* __restrict__ qb, const u16* __restrict__ kb,
    const u16* __restrict__ vt, u16* __restrict__ ob)
{
    __shared__ __align__(16) u16 Ks[2][64 * 128];   // 2 x 16 KiB
    __shared__ __align__(16) u16 Vs[2][128 * 64];   // 2 x 16 KiB
    const int t    = threadIdx.x;
    const int lane = t & 63;
    const int w    = t >> 6;
    const int col  = lane & 15;
    const int g    = lane >> 4;
    const int qt   = 15 - blockIdx.x;     // long tiles dispatch first
    const int qh   = blockIdx.y;
    const int b    = blockIdx.z;
    const int kvh  = qh >> 2;             // G = 4
    const int Q0   = qt * 128;
    const int qw   = Q0 + w * 32;

    // Q fragments (B-operand): Q[q][c*32 + g*8 + j]
    short8 qf[2][4];
#pragma unroll
    for (int sub = 0; sub < 2; sub++) {
        const u16* qrow = qb + ((size_t)(b * 2048 + qw + sub * 16 + col)) * 4096 + qh * 128;
#pragma unroll
        for (int c = 0; c < 4; c++)
            qf[sub][c] = *(const short8*)(qrow + c * 32 + g * 8);
    }

    const u16* kbase = kb + ((size_t)b * 2048) * 1024 + kvh * 128;
    const u16* vbase = vt + ((size_t)kvh * 128) * 4096 + (size_t)b * 2048;

    // ---- staging constants (per-thread, loop-invariant) ----
    // K: per issue i, thread t stages key (t>>4)+i*16, chunk (t&15)^sw(key).
    //    sw(key) = (key&3)^((key&8)>>1); i*16 leaves bits {0,1,3} unchanged.
    const int ksw = ((t >> 4) & 3) ^ (((t >> 4) & 8) >> 1);
    const u16* ksrc0 = kbase + (size_t)(t >> 4) * 1024 + (size_t)((t & 15) ^ ksw) * 8;
    // V: per issue i, thread t stages dim (t>>3)+i*32, LDS chunk cc = t&7,
    //    holding source key-chunk cc ^ (dim&7)  (i*32 leaves dim&7 unchanged).
    const u16* vsrc0 = vbase + (size_t)(t >> 3) * 4096 + (size_t)(((t & 7) ^ ((t >> 3) & 7)) * 8);
    u16* kdst = &Ks[0][0] + t * 8;
    u16* vdst = &Vs[0][0] + t * 8;

    // ---- read constants ----
    // K chunk id for (h,kk,c): key*16 + ((c*4+g)^sw(key)),
    //   key = h*32 + (col>>2)*8 + kk*4 + (col&3); sw depends only on col.
    const int swr = (col & 3) ^ (((col >> 2) & 1) << 2);
    int kb_[2][2];
#pragma unroll
    for (int h = 0; h < 2; h++)
#pragma unroll
        for (int kk = 0; kk < 2; kk++)
            kb_[h][kk] = (h * 32 + (col >> 2) * 8 + kk * 4 + (col & 3)) * 16;
    int cco[4];
#pragma unroll
    for (int c = 0; c < 4; c++) cco[c] = (c * 4 + g) ^ swr;
    // V chunk id for (h,dt): (dt*16+col)*8 + ((h*4+g)^(col&7))
    const int vrow = col * 8;
    const int vcc0 = (g) ^ (col & 7);
    const int vcc1 = (4 + g) ^ (col & 7);

    float m_run[2] = {0.f, 0.f};   // log2-domain running max (deferred)
    float l_run[2] = {0.f, 0.f};
    f32x4 ot[2][8] = {};
    const float SCL = 0.08838834764831845f * 1.4426950408889634f; // 1/sqrt(128)*log2(e)

    const int nsteps = (Q0 + 128) >> 6;
    const int qmax_w = qw + 31;

    auto STAGE = [&](int bufi, int k0i) {
#pragma unroll
        for (int i = 0; i < 4; i++)
            gld16(ksrc0 + (size_t)k0i * 1024 + (size_t)i * 16384, kdst + bufi * 8192 + i * 2048);
#pragma unroll
        for (int i = 0; i < 4; i++)
            gld16(vsrc0 + (size_t)i * 131072 + k0i, vdst + bufi * 8192 + i * 2048);
    };

    int buf = 0;
    STAGE(0, 0);
    __syncthreads();

    for (int step = 0; step < nsteps; step++) {
        const int k0 = step << 6;
        if (step + 1 < nsteps) STAGE(buf ^ 1, k0 + 64);   // prefetch overlaps compute

        if (k0 <= qmax_w) {
            const u16* Kp = &Ks[buf][0];
            const u16* Vp = &Vs[buf][0];

            // scores: 32 MFMAs
            f32x4 sc[2][2][2] = {};   // [sub][h][kk]
            __builtin_amdgcn_s_setprio(1);
#pragma unroll
            for (int h = 0; h < 2; h++)
#pragma unroll
                for (int c = 0; c < 4; c++)
#pragma unroll
                    for (int kk = 0; kk < 2; kk++) {
                        short8 kf = *(const short8*)(Kp + (size_t)(kb_[h][kk] + cco[c]) * 8);
                        sc[0][h][kk] = __builtin_amdgcn_mfma_f32_16x16x32_bf16(kf, qf[0][c], sc[0][h][kk], 0, 0, 0);
                        sc[1][h][kk] = __builtin_amdgcn_mfma_f32_16x16x32_bf16(kf, qf[1][c], sc[1][h][kk], 0, 0, 0);
                    }
            __builtin_amdgcn_s_setprio(0);

            const bool full = (k0 + 63 <= qw);   // wave-uniform: no masking needed
            short8 pf[2][2];
#pragma unroll
            for (int sub = 0; sub < 2; sub++) {
                float s[16];
                float tmax = -1e30f;
                if (full) {
#pragma unroll
                    for (int h = 0; h < 2; h++)
#pragma unroll
                        for (int kk = 0; kk < 2; kk++)
#pragma unroll
                            for (int rr = 0; rr < 4; rr++) {
                                float v = sc[sub][h][kk][rr] * SCL;
                                s[h * 8 + kk * 4 + rr] = v;
                                tmax = fmaxf(tmax, v);
                            }
                } else {
                    const int q = qw + sub * 16 + col;
#pragma unroll
                    for (int h = 0; h < 2; h++)
#pragma unroll
                        for (int kk = 0; kk < 2; kk++)
#pragma unroll
                            for (int rr = 0; rr < 4; rr++) {
                                int key = k0 + h * 32 + g * 8 + kk * 4 + rr;
                                float v = sc[sub][h][kk][rr] * SCL;
                                v = (key <= q) ? v : -1e30f;
                                s[h * 8 + kk * 4 + rr] = v;
                                tmax = fmaxf(tmax, v);
                            }
                }
                tmax = fmaxf(tmax, __shfl_xor(tmax, 16));
                tmax = fmaxf(tmax, __shfl_xor(tmax, 32));
                // deferred rescale: only when tile max beats running max by >8
                if (__any(tmax > m_run[sub] + 8.0f)) {
                    float m_new = fmaxf(m_run[sub], tmax);
                    float alpha = exp2_hw(m_run[sub] - m_new);
                    l_run[sub] *= alpha;
                    m_run[sub] = m_new;
#pragma unroll
                    for (int dt = 0; dt < 8; dt++)
#pragma unroll
                        for (int rr = 0; rr < 4; rr++) ot[sub][dt][rr] *= alpha;
                }
                const float m = m_run[sub];
                float tsum = 0.f;
#pragma unroll
                for (int j = 0; j < 16; j++) {
                    s[j] = exp2_hw(s[j] - m);   // masked lanes: 2^(-huge) -> 0
                    tsum += s[j];
                }
#pragma unroll
                for (int h = 0; h < 2; h++)
#pragma unroll
                    for (int jw = 0; jw < 4; jw++)
                        ((u32*)&pf[sub][h])[jw] = cvtpk_bf16(s[h * 8 + jw * 2], s[h * 8 + jw * 2 + 1]);
                tsum += __shfl_xor(tsum, 16);
                tsum += __shfl_xor(tsum, 32);
                l_run[sub] += tsum;
            }

            // PV: 32 MFMAs, O^T += V^T * P^T
            __builtin_amdgcn_s_setprio(1);
#pragma unroll
            for (int dt = 0; dt < 8; dt++) {
                short8 vf0 = *(const short8*)(Vp + (size_t)(dt * 128 + vrow + vcc0) * 8);
                short8 vf1 = *(const short8*)(Vp + (size_t)(dt * 128 + vrow + vcc1) * 8);
                ot[0][dt] = __builtin_amdgcn_mfma_f32_16x16x32_bf16(vf0, pf[0][0], ot[0][dt], 0, 0, 0);
                ot[1][dt] = __builtin_amdgcn_mfma_f32_16x16x32_bf16(vf0, pf[1][0], ot[1][dt], 0, 0, 0);
                ot[0][dt] = __builtin_amdgcn_mfma_f32_16x16x32_bf16(vf1, pf[0][1], ot[0][dt], 0, 0, 0);
                ot[1][dt] = __builtin_amdgcn_mfma_f32_16x16x32_bf16(vf1, pf[1][1], ot[1][dt], 0, 0, 0);
            }
            __builtin_amdgcn_s_setprio(0);
        }
        __syncthreads();   // drains prefetch (vmcnt 0) + guards buffer reuse
        buf ^= 1;
    }

    // epilogue: O^T C-layout: dim = dt*16 + g*4 + rr, query = col
#pragma unroll
    for (int sub = 0; sub < 2; sub++) {
        float inv = 1.0f / l_run[sub];
        u16* orow = ob + ((size_t)(b * 2048 + qw + sub * 16 + col)) * 4096 + qh * 128;
#pragma unroll
        for (int dt = 0; dt < 8; dt++) {
            ushort4_t o;
#pragma unroll
            for (int rr = 0; rr < 4; rr++) o[rr] = f2bf(ot[sub][dt][rr] * inv);
            *(ushort4_t*)(orow + dt * 16 + g * 4) = o;
        }
    }
}

// ---------------------------------------------------------------------------
extern "C" void kernel_launch(void* const* d_in, const int* in_sizes, int n_in,
                              void* d_out, int out_size, void* d_ws, size_t ws_size,
                              hipStream_t stream) {
    const float* hs = (const float*)d_in[0];  // [2,2048,4096]
    const float* Wq = (const float*)d_in[1];  // [4096,4096]
    const float* Wk = (const float*)d_in[2];  // [1024,4096]
    const float* Wv = (const float*)d_in[3];  // [1024,4096]
    const float* Wo = (const float*)d_in[4];  // [4096,4096]
    float* out = (float*)d_out;               // [2,2048,4096]

    char* ws = (char*)d_ws;
    u16* hsb = (u16*)(ws + 0);           // [4096,4096] bf16
    u16* Wqb = (u16*)(ws + 33554432);
    u16* Wkb = (u16*)(ws + 67108864);
    u16* Wvb = (u16*)(ws + 75497472);
    u16* Wob = (u16*)(ws + 83886080);
    u16* qb  = (u16*)(ws + 117440512);   // [4096,4096] bf16
    u16* kbf = (u16*)(ws + 150994944);   // [4096,1024] bf16
    u16* vtb = (u16*)(ws + 159383552);   // [1024,4096] bf16 (V transposed)
    u16* ab  = hsb;                      // alias: hs dead after QKV GEMMs

    cvt_f32_bf16<<<16384, 256, 0, stream>>>(hs, hsb, 4194304);
    cvt_f32_bf16<<<16384, 256, 0, stream>>>(Wq, Wqb, 4194304);
    cvt_f32_bf16<<<4096,  256, 0, stream>>>(Wk, Wkb, 1048576);
    cvt_f32_bf16<<<4096,  256, 0, stream>>>(Wv, Wvb, 1048576);
    cvt_f32_bf16<<<16384, 256, 0, stream>>>(Wo, Wob, 4194304);

    gemm_bt<0><<<dim3(32, 32), 256, 0, stream>>>(hsb, Wqb, qb,  nullptr, 4096, 4096, 4096);
    gemm_bt<0><<<dim3(8, 32),  256, 0, stream>>>(hsb, Wkb, kbf, nullptr, 4096, 1024, 4096);
    gemm_bt<3><<<dim3(8, 32),  256, 0, stream>>>(hsb, Wvb, vtb, nullptr, 4096, 1024, 4096);

    rope_k<<<32768, 256, 0, stream>>>(qb,  11);
    rope_k<<<8192,  256, 0, stream>>>(kbf, 9);

    flash_attn<<<dim3(16, 32, 2), 256, 0, stream>>>(qb, kbf, vtb, ab);

    gemm_bt<1><<<dim3(32, 32), 256, 0, stream>>>(ab, Wob, nullptr, out, 4096, 4096, 4096);
}

// Round 2
// 1057.655 us; speedup vs baseline: 1.1119x; 1.1119x over previous
//
#include <hip/hip_runtime.h>

typedef unsigned short u16;
typedef unsigned int u32;
typedef __attribute__((ext_vector_type(8))) short short8;
typedef __attribute__((ext_vector_type(4))) float f32x4;
typedef __attribute__((ext_vector_type(4))) u16 ushort4_t;

// ---------- scalar conversion helpers --------------------------------------
__device__ __forceinline__ float bf2f(u16 u) {
    u32 x = ((u32)u) << 16;
    return __uint_as_float(x);
}
__device__ __forceinline__ u16 f2bf(float f) {  // round-to-nearest-even
    u32 x = __float_as_uint(f);
    x += 0x7FFFu + ((x >> 16) & 1u);
    return (u16)(x >> 16);
}
// packed f32x2 -> bf16x2 (RNE), gfx950 HW instruction
__device__ __forceinline__ u32 cvtpk_bf16(float lo, float hi) {
    u32 r;
    asm("v_cvt_pk_bf16_f32 %0, %1, %2" : "=v"(r) : "v"(lo), "v"(hi));
    return r;
}
// 2^x via HW transcendental (no libm guard code)
__device__ __forceinline__ float exp2_hw(float x) {
    float r;
    asm("v_exp_f32 %0, %1" : "=v"(r) : "v"(x));
    return r;
}

// ---------- async global->LDS (16B per lane, wave-uniform base) ------------
using as1_cv = __attribute__((address_space(1))) const void;
using as3_v  = __attribute__((address_space(3))) void;
__device__ __forceinline__ void gld16(const void* g, void* l) {
    __builtin_amdgcn_global_load_lds((as1_cv*)g, (as3_v*)l, 16, 0, 0);
}

// ---------- fp32 -> bf16 convert (4 elems/thread) --------------------------
__global__ void cvt_f32_bf16(const float* __restrict__ in, u16* __restrict__ out, int n4) {
    int i = blockIdx.x * 256 + threadIdx.x;
    if (i >= n4) return;
    float4 v = ((const float4*)in)[i];
    ushort4_t o;
    o[0] = f2bf(v.x); o[1] = f2bf(v.y); o[2] = f2bf(v.z); o[3] = f2bf(v.w);
    ((ushort4_t*)out)[i] = o;
}

// ---------- GEMM: C[M,N] = A[M,K] * B[N,K]^T, bf16 inputs ------------------
// OUT_MODE: 0 = bf16 out, 1 = f32 out, 3 = bf16 TRANSPOSED out (Ct[N,M])
template <int OUT_MODE>
__global__ __launch_bounds__(256) void gemm_bt(
    const u16* __restrict__ A, const u16* __restrict__ B,
    u16* __restrict__ Cb, float* __restrict__ Cf,
    int M, int N, int K)
{
    __shared__ __align__(16) u16 As[128 * 32];
    __shared__ __align__(16) u16 Bs[128 * 32];
    const int t    = threadIdx.x;
    const int lane = t & 63;
    const int w    = t >> 6;
    const int wm   = w & 1;
    const int wn   = w >> 1;
    const int bx   = blockIdx.x;   // N tile
    const int by   = blockIdx.y;   // M tile

    const int r  = t >> 2;
    const int c8 = (t & 3) * 8;
    const u16* gA0 = A + (size_t)(by * 128 + r) * K + c8;
    const u16* gA1 = gA0 + (size_t)64 * K;
    const u16* gB0 = B + (size_t)(bx * 128 + r) * K + c8;
    const u16* gB1 = gB0 + (size_t)64 * K;
    u16* lA0 = &As[t * 8];
    u16* lA1 = &As[2048 + t * 8];
    u16* lB0 = &Bs[t * 8];
    u16* lB1 = &Bs[2048 + t * 8];

    f32x4 acc[4][4] = {};

    const int arow = wm * 64 + (lane & 15);
    const int brow = wn * 64 + (lane & 15);
    const int koff = (lane >> 4) * 8;

    for (int kt = 0; kt < K; kt += 32) {
        gld16(gA0 + kt, lA0);
        gld16(gA1 + kt, lA1);
        gld16(gB0 + kt, lB0);
        gld16(gB1 + kt, lB1);
        __syncthreads();
        short8 af[4], bf[4];
#pragma unroll
        for (int i = 0; i < 4; i++)
            af[i] = *(const short8*)&As[(arow + i * 16) * 32 + koff];
#pragma unroll
        for (int i = 0; i < 4; i++)
            bf[i] = *(const short8*)&Bs[(brow + i * 16) * 32 + koff];
#pragma unroll
        for (int mi = 0; mi < 4; mi++)
#pragma unroll
            for (int ni = 0; ni < 4; ni++)
                acc[mi][ni] = __builtin_amdgcn_mfma_f32_16x16x32_bf16(
                    af[mi], bf[ni], acc[mi][ni], 0, 0, 0);
        __syncthreads();
    }

    const int row0 = by * 128 + wm * 64 + (lane >> 4) * 4;
    const int col0 = bx * 128 + wn * 64 + (lane & 15);
#pragma unroll
    for (int mi = 0; mi < 4; mi++) {
#pragma unroll
        for (int ni = 0; ni < 4; ni++) {
            if (OUT_MODE == 3) {
                // transposed bf16: Ct[col][row], 4 consecutive rows -> 8B store
                ushort4_t o;
#pragma unroll
                for (int rr = 0; rr < 4; rr++) o[rr] = f2bf(acc[mi][ni][rr]);
                int col = col0 + ni * 16;
                *(ushort4_t*)&Cb[(size_t)col * M + row0 + mi * 16] = o;
            } else {
#pragma unroll
                for (int rr = 0; rr < 4; rr++) {
                    int row = row0 + mi * 16 + rr;
                    int col = col0 + ni * 16;
                    float v = acc[mi][ni][rr];
                    if (OUT_MODE == 1) Cf[(size_t)row * N + col] = v;
                    else               Cb[(size_t)row * N + col] = f2bf(v);
                }
            }
        }
    }
}

// ---------- RoPE in-place on bf16 [B*S, H*128] -----------------------------
__global__ void rope_k(u16* __restrict__ x, int hshift) {
    int idx = blockIdx.x * 256 + threadIdx.x;
    int i   = idx & 63;
    int hm  = (1 << (hshift - 6)) - 1;
    int h   = (idx >> 6) & hm;
    int row = idx >> hshift;       // 0..B*S-1
    int s   = row & 2047;          // position within sequence
    int stride = (hm + 1) * 128;
    size_t base = (size_t)row * stride + h * 128 + i;
    float th = (float)s * powf(10000.0f, -(float)i / 64.0f);
    float cs = cosf(th), sn = sinf(th);
    float x1 = bf2f(x[base]), x2 = bf2f(x[base + 64]);
    x[base]      = f2bf(x1 * cs - x2 * sn);
    x[base + 64] = f2bf(x2 * cs + x1 * sn);
}

// ---------- causal flash attention -----------------------------------------
// grid (8, NH, B); 256 thr = 4 waves; KVBLK = 64, double-buffered LDS.
// LOAD BALANCE: causal work is triangular (q-tile qt costs qt+1 units), so
// each block processes a COMPLEMENTARY PAIR of 128-row q-tiles:
//   phase 0: qt = 8 + p (long),  phase 1: qt = 7 - p (short)
// -> every block does exactly 34 64-key steps; 512 uniform blocks = 2/CU,
// all resident start-to-finish (the round-1 single-tile grid decayed to ~2
// resident waves/CU from the triangular drain tail -> 70% idle cycles).
// scores: S^T = Kperm * Q^T  (A rows permuted: key(m) = (m>>2)*8+kk*4+(m&3))
//   -> C rows land exactly in PV B-operand key order g*8+j.
// PV: O^T += V^T * P^T, V^T staged [dim][64key] with per-row XOR swizzle
//   cc ^= (dim&7) (bank-spread; conflict floor only).
// Softmax: log2 domain (v_exp_f32), one reduce per 64 keys, deferred rescale.
__global__ __launch_bounds__(256) void flash_attn(
    const u16* __restrict__ qb, const u16* __restrict__ kb,
    const u16* __restrict__ vt, u16* __restrict__ ob)
{
    __shared__ __align__(16) u16 Ks[2][64 * 128];   // 2 x 16 KiB
    __shared__ __align__(16) u16 Vs[2][128 * 64];   // 2 x 16 KiB
    const int t    = threadIdx.x;
    const int lane = t & 63;
    const int w    = t >> 6;
    const int col  = lane & 15;
    const int g    = lane >> 4;
    const int p    = blockIdx.x;          // pair id 0..7
    const int qh   = blockIdx.y;
    const int b    = blockIdx.z;
    const int kvh  = qh >> 2;             // G = 4

    const u16* kbase = kb + ((size_t)b * 2048) * 1024 + kvh * 128;
    const u16* vbase = vt + ((size_t)kvh * 128) * 4096 + (size_t)b * 2048;

    // ---- staging constants (per-thread, phase-invariant) ----
    // K: per issue i, thread t stages key (t>>4)+i*16, chunk (t&15)^sw(key).
    //    sw(key) = (key&3)^((key&8)>>1); i*16 leaves bits {0,1,3} unchanged.
    const int ksw = ((t >> 4) & 3) ^ (((t >> 4) & 8) >> 1);
    const u16* ksrc0 = kbase + (size_t)(t >> 4) * 1024 + (size_t)((t & 15) ^ ksw) * 8;
    // V: per issue i, thread t stages dim (t>>3)+i*32, LDS chunk cc = t&7,
    //    holding source key-chunk cc ^ (dim&7)  (i*32 leaves dim&7 unchanged).
    const u16* vsrc0 = vbase + (size_t)(t >> 3) * 4096 + (size_t)(((t & 7) ^ ((t >> 3) & 7)) * 8);
    u16* kdst = &Ks[0][0] + t * 8;
    u16* vdst = &Vs[0][0] + t * 8;

    // ---- read constants ----
    // K chunk id for (h,kk,c): key*16 + ((c*4+g)^sw(key)),
    //   key = h*32 + (col>>2)*8 + kk*4 + (col&3); sw depends only on col.
    const int swr = (col & 3) ^ (((col >> 2) & 1) << 2);
    int kb_[2][2];
#pragma unroll
    for (int h = 0; h < 2; h++)
#pragma unroll
        for (int kk = 0; kk < 2; kk++)
            kb_[h][kk] = (h * 32 + (col >> 2) * 8 + kk * 4 + (col & 3)) * 16;
    int cco[4];
#pragma unroll
    for (int c = 0; c < 4; c++) cco[c] = (c * 4 + g) ^ swr;
    // V chunk id for (h,dt): (dt*16+col)*8 + ((h*4+g)^(col&7))
    const int vrow = col * 8;
    const int vcc0 = (g) ^ (col & 7);
    const int vcc1 = (4 + g) ^ (col & 7);

    const float SCL = 0.08838834764831845f * 1.4426950408889634f; // 1/sqrt(128)*log2(e)

    auto STAGE = [&](int bufi, int k0i) {
#pragma unroll
        for (int i = 0; i < 4; i++)
            gld16(ksrc0 + (size_t)k0i * 1024 + (size_t)i * 16384, kdst + bufi * 8192 + i * 2048);
#pragma unroll
        for (int i = 0; i < 4; i++)
            gld16(vsrc0 + (size_t)i * 131072 + k0i, vdst + bufi * 8192 + i * 2048);
    };

#pragma unroll 1
    for (int phase = 0; phase < 2; phase++) {
        const int qt = phase ? (7 - p) : (8 + p);
        const int Q0 = qt * 128;
        const int qw = Q0 + w * 32;

        // Q fragments (B-operand): Q[q][c*32 + g*8 + j]
        short8 qf[2][4];
#pragma unroll
        for (int sub = 0; sub < 2; sub++) {
            const u16* qrow = qb + ((size_t)(b * 2048 + qw + sub * 16 + col)) * 4096 + qh * 128;
#pragma unroll
            for (int c = 0; c < 4; c++)
                qf[sub][c] = *(const short8*)(qrow + c * 32 + g * 8);
        }

        float m_run[2] = {0.f, 0.f};   // log2-domain running max (deferred)
        float l_run[2] = {0.f, 0.f};
        f32x4 ot[2][8] = {};

        const int nsteps = (Q0 + 128) >> 6;
        const int qmax_w = qw + 31;

        int buf = 0;
        STAGE(0, 0);
        __syncthreads();

        for (int step = 0; step < nsteps; step++) {
            const int k0 = step << 6;
            if (step + 1 < nsteps) STAGE(buf ^ 1, k0 + 64);   // prefetch overlaps compute

            if (k0 <= qmax_w) {
                const u16* Kp = &Ks[buf][0];
                const u16* Vp = &Vs[buf][0];

                // scores: 32 MFMAs
                f32x4 sc[2][2][2] = {};   // [sub][h][kk]
                __builtin_amdgcn_s_setprio(1);
#pragma unroll
                for (int h = 0; h < 2; h++)
#pragma unroll
                    for (int c = 0; c < 4; c++)
#pragma unroll
                        for (int kk = 0; kk < 2; kk++) {
                            short8 kf = *(const short8*)(Kp + (size_t)(kb_[h][kk] + cco[c]) * 8);
                            sc[0][h][kk] = __builtin_amdgcn_mfma_f32_16x16x32_bf16(kf, qf[0][c], sc[0][h][kk], 0, 0, 0);
                            sc[1][h][kk] = __builtin_amdgcn_mfma_f32_16x16x32_bf16(kf, qf[1][c], sc[1][h][kk], 0, 0, 0);
                        }
                __builtin_amdgcn_s_setprio(0);

                const bool full = (k0 + 63 <= qw);   // wave-uniform: no masking needed
                short8 pf[2][2];
#pragma unroll
                for (int sub = 0; sub < 2; sub++) {
                    float s[16];
                    float tmax = -1e30f;
                    if (full) {
#pragma unroll
                        for (int h = 0; h < 2; h++)
#pragma unroll
                            for (int kk = 0; kk < 2; kk++)
#pragma unroll
                                for (int rr = 0; rr < 4; rr++) {
                                    float v = sc[sub][h][kk][rr] * SCL;
                                    s[h * 8 + kk * 4 + rr] = v;
                                    tmax = fmaxf(tmax, v);
                                }
                    } else {
                        const int q = qw + sub * 16 + col;
#pragma unroll
                        for (int h = 0; h < 2; h++)
#pragma unroll
                            for (int kk = 0; kk < 2; kk++)
#pragma unroll
                                for (int rr = 0; rr < 4; rr++) {
                                    int key = k0 + h * 32 + g * 8 + kk * 4 + rr;
                                    float v = sc[sub][h][kk][rr] * SCL;
                                    v = (key <= q) ? v : -1e30f;
                                    s[h * 8 + kk * 4 + rr] = v;
                                    tmax = fmaxf(tmax, v);
                                }
                    }
                    tmax = fmaxf(tmax, __shfl_xor(tmax, 16));
                    tmax = fmaxf(tmax, __shfl_xor(tmax, 32));
                    // deferred rescale: only when tile max beats running max by >8
                    if (__any(tmax > m_run[sub] + 8.0f)) {
                        float m_new = fmaxf(m_run[sub], tmax);
                        float alpha = exp2_hw(m_run[sub] - m_new);
                        l_run[sub] *= alpha;
                        m_run[sub] = m_new;
#pragma unroll
                        for (int dt = 0; dt < 8; dt++)
#pragma unroll
                            for (int rr = 0; rr < 4; rr++) ot[sub][dt][rr] *= alpha;
                    }
                    const float m = m_run[sub];
                    float tsum = 0.f;
#pragma unroll
                    for (int j = 0; j < 16; j++) {
                        s[j] = exp2_hw(s[j] - m);   // masked lanes: 2^(-huge) -> 0
                        tsum += s[j];
                    }
#pragma unroll
                    for (int h = 0; h < 2; h++)
#pragma unroll
                        for (int jw = 0; jw < 4; jw++)
                            ((u32*)&pf[sub][h])[jw] = cvtpk_bf16(s[h * 8 + jw * 2], s[h * 8 + jw * 2 + 1]);
                    tsum += __shfl_xor(tsum, 16);
                    tsum += __shfl_xor(tsum, 32);
                    l_run[sub] += tsum;
                }

                // PV: 32 MFMAs, O^T += V^T * P^T
                __builtin_amdgcn_s_setprio(1);
#pragma unroll
                for (int dt = 0; dt < 8; dt++) {
                    short8 vf0 = *(const short8*)(Vp + (size_t)(dt * 128 + vrow + vcc0) * 8);
                    short8 vf1 = *(const short8*)(Vp + (size_t)(dt * 128 + vrow + vcc1) * 8);
                    ot[0][dt] = __builtin_amdgcn_mfma_f32_16x16x32_bf16(vf0, pf[0][0], ot[0][dt], 0, 0, 0);
                    ot[1][dt] = __builtin_amdgcn_mfma_f32_16x16x32_bf16(vf0, pf[1][0], ot[1][dt], 0, 0, 0);
                    ot[0][dt] = __builtin_amdgcn_mfma_f32_16x16x32_bf16(vf1, pf[0][1], ot[0][dt], 0, 0, 0);
                    ot[1][dt] = __builtin_amdgcn_mfma_f32_16x16x32_bf16(vf1, pf[1][1], ot[1][dt], 0, 0, 0);
                }
                __builtin_amdgcn_s_setprio(0);
            }
            __syncthreads();   // drains prefetch (vmcnt 0) + guards buffer reuse
            buf ^= 1;
        }

        // epilogue: O^T C-layout: dim = dt*16 + g*4 + rr, query = col
        // (register/global only -- no LDS access, so next phase may restage
        //  immediately after the loop's final __syncthreads)
#pragma unroll
        for (int sub = 0; sub < 2; sub++) {
            float inv = 1.0f / l_run[sub];
            u16* orow = ob + ((size_t)(b * 2048 + qw + sub * 16 + col)) * 4096 + qh * 128;
#pragma unroll
            for (int dt = 0; dt < 8; dt++) {
                ushort4_t o;
#pragma unroll
                for (int rr = 0; rr < 4; rr++) o[rr] = f2bf(ot[sub][dt][rr] * inv);
                *(ushort4_t*)(orow + dt * 16 + g * 4) = o;
            }
        }
    }
}

// ---------------------------------------------------------------------------
extern "C" void kernel_launch(void* const* d_in, const int* in_sizes, int n_in,
                              void* d_out, int out_size, void* d_ws, size_t ws_size,
                              hipStream_t stream) {
    const float* hs = (const float*)d_in[0];  // [2,2048,4096]
    const float* Wq = (const float*)d_in[1];  // [4096,4096]
    const float* Wk = (const float*)d_in[2];  // [1024,4096]
    const float* Wv = (const float*)d_in[3];  // [1024,4096]
    const float* Wo = (const float*)d_in[4];  // [4096,4096]
    float* out = (float*)d_out;               // [2,2048,4096]

    char* ws = (char*)d_ws;
    u16* hsb = (u16*)(ws + 0);           // [4096,4096] bf16
    u16* Wqb = (u16*)(ws + 33554432);
    u16* Wkb = (u16*)(ws + 67108864);
    u16* Wvb = (u16*)(ws + 75497472);
    u16* Wob = (u16*)(ws + 83886080);
    u16* qb  = (u16*)(ws + 117440512);   // [4096,4096] bf16
    u16* kbf = (u16*)(ws + 150994944);   // [4096,1024] bf16
    u16* vtb = (u16*)(ws + 159383552);   // [1024,4096] bf16 (V transposed)
    u16* ab  = hsb;                      // alias: hs dead after QKV GEMMs

    cvt_f32_bf16<<<16384, 256, 0, stream>>>(hs, hsb, 4194304);
    cvt_f32_bf16<<<16384, 256, 0, stream>>>(Wq, Wqb, 4194304);
    cvt_f32_bf16<<<4096,  256, 0, stream>>>(Wk, Wkb, 1048576);
    cvt_f32_bf16<<<4096,  256, 0, stream>>>(Wv, Wvb, 1048576);
    cvt_f32_bf16<<<16384, 256, 0, stream>>>(Wo, Wob, 4194304);

    gemm_bt<0><<<dim3(32, 32), 256, 0, stream>>>(hsb, Wqb, qb,  nullptr, 4096, 4096, 4096);
    gemm_bt<0><<<dim3(8, 32),  256, 0, stream>>>(hsb, Wkb, kbf, nullptr, 4096, 1024, 4096);
    gemm_bt<3><<<dim3(8, 32),  256, 0, stream>>>(hsb, Wvb, vtb, nullptr, 4096, 1024, 4096);

    rope_k<<<32768, 256, 0, stream>>>(qb,  11);
    rope_k<<<8192,  256, 0, stream>>>(kbf, 9);

    flash_attn<<<dim3(8, 32, 2), 256, 0, stream>>>(qb, kbf, vtb, ab);

    gemm_bt<1><<<dim3(32, 32), 256, 0, stream>>>(ab, Wob, nullptr, out, 4096, 4096, 4096);
}

// Round 3
// 845.550 us; speedup vs baseline: 1.3908x; 1.2508x over previous
//
#include <hip/hip_runtime.h>

typedef unsigned short u16;
typedef unsigned int u32;
typedef __attribute__((ext_vector_type(8))) short short8;
typedef __attribute__((ext_vector_type(4))) float f32x4;
typedef __attribute__((ext_vector_type(4))) u16 ushort4_t;

// ---------- scalar conversion helpers --------------------------------------
__device__ __forceinline__ float bf2f(u16 u) {
    u32 x = ((u32)u) << 16;
    return __uint_as_float(x);
}
__device__ __forceinline__ u16 f2bf(float f) {  // round-to-nearest-even
    u32 x = __float_as_uint(f);
    x += 0x7FFFu + ((x >> 16) & 1u);
    return (u16)(x >> 16);
}
// packed f32x2 -> bf16x2 (RNE), gfx950 HW instruction
__device__ __forceinline__ u32 cvtpk_bf16(float lo, float hi) {
    u32 r;
    asm("v_cvt_pk_bf16_f32 %0, %1, %2" : "=v"(r) : "v"(lo), "v"(hi));
    return r;
}
// 2^x via HW transcendental (no libm guard code)
__device__ __forceinline__ float exp2_hw(float x) {
    float r;
    asm("v_exp_f32 %0, %1" : "=v"(r) : "v"(x));
    return r;
}

// ---------- async global->LDS (16B per lane, wave-uniform base) ------------
using as1_cv = __attribute__((address_space(1))) const void;
using as3_v  = __attribute__((address_space(3))) void;
__device__ __forceinline__ void gld16(const void* g, void* l) {
    __builtin_amdgcn_global_load_lds((as1_cv*)g, (as3_v*)l, 16, 0, 0);
}

// ---------- fp32 -> bf16 convert (4 elems/thread) --------------------------
__global__ void cvt_f32_bf16(const float* __restrict__ in, u16* __restrict__ out, int n4) {
    int i = blockIdx.x * 256 + threadIdx.x;
    if (i >= n4) return;
    float4 v = ((const float4*)in)[i];
    ushort4_t o;
    o[0] = f2bf(v.x); o[1] = f2bf(v.y); o[2] = f2bf(v.z); o[3] = f2bf(v.w);
    ((ushort4_t*)out)[i] = o;
}

// ---------- GEMM (128x128 tile): C[M,N] = A[M,K] * B[N,K]^T ----------------
// OUT_MODE: 0 = bf16 out, 1 = f32 out, 3 = bf16 TRANSPOSED out (Ct[N,M])
template <int OUT_MODE>
__global__ __launch_bounds__(256) void gemm_bt(
    const u16* __restrict__ A, const u16* __restrict__ B,
    u16* __restrict__ Cb, float* __restrict__ Cf,
    int M, int N, int K)
{
    __shared__ __align__(16) u16 As[128 * 32];
    __shared__ __align__(16) u16 Bs[128 * 32];
    const int t    = threadIdx.x;
    const int lane = t & 63;
    const int w    = t >> 6;
    const int wm   = w & 1;
    const int wn   = w >> 1;
    const int bx   = blockIdx.x;   // N tile
    const int by   = blockIdx.y;   // M tile

    const int r  = t >> 2;
    const int c8 = (t & 3) * 8;
    const u16* gA0 = A + (size_t)(by * 128 + r) * K + c8;
    const u16* gA1 = gA0 + (size_t)64 * K;
    const u16* gB0 = B + (size_t)(bx * 128 + r) * K + c8;
    const u16* gB1 = gB0 + (size_t)64 * K;
    u16* lA0 = &As[t * 8];
    u16* lA1 = &As[2048 + t * 8];
    u16* lB0 = &Bs[t * 8];
    u16* lB1 = &Bs[2048 + t * 8];

    f32x4 acc[4][4] = {};

    const int arow = wm * 64 + (lane & 15);
    const int brow = wn * 64 + (lane & 15);
    const int koff = (lane >> 4) * 8;

    for (int kt = 0; kt < K; kt += 32) {
        gld16(gA0 + kt, lA0);
        gld16(gA1 + kt, lA1);
        gld16(gB0 + kt, lB0);
        gld16(gB1 + kt, lB1);
        __syncthreads();
        short8 af[4], bf[4];
#pragma unroll
        for (int i = 0; i < 4; i++)
            af[i] = *(const short8*)&As[(arow + i * 16) * 32 + koff];
#pragma unroll
        for (int i = 0; i < 4; i++)
            bf[i] = *(const short8*)&Bs[(brow + i * 16) * 32 + koff];
#pragma unroll
        for (int mi = 0; mi < 4; mi++)
#pragma unroll
            for (int ni = 0; ni < 4; ni++)
                acc[mi][ni] = __builtin_amdgcn_mfma_f32_16x16x32_bf16(
                    af[mi], bf[ni], acc[mi][ni], 0, 0, 0);
        __syncthreads();
    }

    const int row0 = by * 128 + wm * 64 + (lane >> 4) * 4;
    const int col0 = bx * 128 + wn * 64 + (lane & 15);
#pragma unroll
    for (int mi = 0; mi < 4; mi++) {
#pragma unroll
        for (int ni = 0; ni < 4; ni++) {
            if (OUT_MODE == 3) {
                // transposed bf16: Ct[col][row], 4 consecutive rows -> 8B store
                ushort4_t o;
#pragma unroll
                for (int rr = 0; rr < 4; rr++) o[rr] = f2bf(acc[mi][ni][rr]);
                int col = col0 + ni * 16;
                *(ushort4_t*)&Cb[(size_t)col * M + row0 + mi * 16] = o;
            } else {
#pragma unroll
                for (int rr = 0; rr < 4; rr++) {
                    int row = row0 + mi * 16 + rr;
                    int col = col0 + ni * 16;
                    float v = acc[mi][ni][rr];
                    if (OUT_MODE == 1) Cf[(size_t)row * N + col] = v;
                    else               Cb[(size_t)row * N + col] = f2bf(v);
                }
            }
        }
    }
}

// ---------- GEMM (256x256 tile, BK=32, ring-4 LDS, counted vmcnt) ----------
// 512 thr = 8 waves (2M x 4N), per-wave 128x64 output (acc[8][4]).
// LDS: 4 ring slots x (A 16KB + B 16KB) = 128 KiB -> 1 block/CU, grid 16x16
// = 256 blocks = exactly 1/CU for 4096^2 output.
// Schedule per K-tile: s_waitcnt vmcnt(8) (tiles kt+1,kt+2 stay in flight;
// NEVER vmcnt(0) in steady state) -> s_barrier -> issue stage of tile kt+3
// (slot that held kt-1: all waves finished reading it before this barrier,
// since their ds_reads retired pre-barrier via lgkm waits) -> ds_read frags
// -> MFMA (setprio).
// LDS layout per operand tile: 16 subtiles of [16 rows][32 k] (1 KiB each);
// within a subtile, 16B chunks are XOR-permuted: chunk ^= (chunk>>4)&3.
// Read side: quarter-wave (16 lanes, g fixed) ds_read_b128 starts then cover
// all 8 bank-quads, 2 lanes each = conflict-free. Staging stays linear in t
// (global_load_lds requirement); the inverse permutation is folded into the
// per-thread GLOBAL source k-offset (involution, bits 0-1 of chunk id only).
template <int OUT_MODE>   // 0 = bf16 out, 1 = f32 out
__global__ __launch_bounds__(512, 2) void gemm_bt256(
    const u16* __restrict__ A, const u16* __restrict__ B,
    u16* __restrict__ Cb, float* __restrict__ Cf,
    int M, int N, int K)
{
    __shared__ __align__(16) u16 S[65536];   // 4 slots x 16384 u16 (A: +0, B: +8192)
    const int t    = threadIdx.x;
    const int lane = t & 63;
    const int w    = t >> 6;
    const int wm   = w >> 2;        // 0..1
    const int wn   = w & 3;         // 0..3
    const int col  = lane & 15;
    const int g    = lane >> 4;

    // staging source: thread t stages rows (t>>2) and (t>>2)+128;
    // source k-chunk carries the inverse swizzle: kel = ((t&3)^((t>>4)&3))*8
    const int kel = (((t & 3) ^ ((t >> 4) & 3)) * 8);
    const u16* gA = A + (size_t)(blockIdx.y * 256 + (t >> 2)) * K + kel;
    const u16* gB = B + (size_t)(blockIdx.x * 256 + (t >> 2)) * K + kel;
    const size_t rstride = (size_t)128 * K;
    u16* ldsA = &S[t * 8];
    u16* ldsB = &S[8192 + t * 8];

    // read offset within a subtile (u16 units): swizzled chunk * 8
    const int rchunk = (((col * 4 + g) ^ ((col >> 2) & 3)) * 8);
    int aoff[8], boff[4];
#pragma unroll
    for (int mi = 0; mi < 8; mi++) aoff[mi] = (wm * 8 + mi) * 512 + rchunk;
#pragma unroll
    for (int ni = 0; ni < 4; ni++) boff[ni] = 8192 + (wn * 4 + ni) * 512 + rchunk;

    f32x4 acc[8][4] = {};

    auto STAGE = [&](int slot, int kt) {
        const size_t so = (size_t)slot * 16384;
        gld16(gA + kt,            ldsA + so);
        gld16(gA + kt + rstride,  ldsA + so + 4096);
        gld16(gB + kt,            ldsB + so);
        gld16(gB + kt + rstride,  ldsB + so + 4096);
    };

    const int NT = K >> 5;   // 128 K-tiles of 32
    STAGE(0, 0);
    STAGE(1, 32);
    STAGE(2, 64);

    for (int kt = 0; kt < NT; kt++) {
        // counted wait: tile kt complete; kt+1/kt+2 (4 loads each) in flight
        if (kt < NT - 2)      asm volatile("s_waitcnt vmcnt(8)" ::: "memory");
        else if (kt < NT - 1) asm volatile("s_waitcnt vmcnt(4)" ::: "memory");
        else                  asm volatile("s_waitcnt vmcnt(0)" ::: "memory");
        __builtin_amdgcn_s_barrier();
        asm volatile("" ::: "memory");
        if (kt < NT - 3) STAGE((kt + 3) & 3, (kt + 3) << 5);

        const u16* Sb = &S[(kt & 3) * 16384];
        short8 af[8], bf[4];
#pragma unroll
        for (int mi = 0; mi < 8; mi++) af[mi] = *(const short8*)(Sb + aoff[mi]);
#pragma unroll
        for (int ni = 0; ni < 4; ni++) bf[ni] = *(const short8*)(Sb + boff[ni]);

        __builtin_amdgcn_s_setprio(1);
#pragma unroll
        for (int mi = 0; mi < 8; mi++)
#pragma unroll
            for (int ni = 0; ni < 4; ni++)
                acc[mi][ni] = __builtin_amdgcn_mfma_f32_16x16x32_bf16(
                    af[mi], bf[ni], acc[mi][ni], 0, 0, 0);
        __builtin_amdgcn_s_setprio(0);
    }

    const int row0 = blockIdx.y * 256 + wm * 128 + (lane >> 4) * 4;
    const int col0 = blockIdx.x * 256 + wn * 64 + (lane & 15);
#pragma unroll
    for (int mi = 0; mi < 8; mi++) {
#pragma unroll
        for (int ni = 0; ni < 4; ni++) {
#pragma unroll
            for (int rr = 0; rr < 4; rr++) {
                int row = row0 + mi * 16 + rr;
                int col = col0 + ni * 16;
                float v = acc[mi][ni][rr];
                if (OUT_MODE == 1) Cf[(size_t)row * N + col] = v;
                else               Cb[(size_t)row * N + col] = f2bf(v);
            }
        }
    }
}

// ---------- RoPE in-place on bf16 [B*S, H*128] -----------------------------
__global__ void rope_k(u16* __restrict__ x, int hshift) {
    int idx = blockIdx.x * 256 + threadIdx.x;
    int i   = idx & 63;
    int hm  = (1 << (hshift - 6)) - 1;
    int h   = (idx >> 6) & hm;
    int row = idx >> hshift;       // 0..B*S-1
    int s   = row & 2047;          // position within sequence
    int stride = (hm + 1) * 128;
    size_t base = (size_t)row * stride + h * 128 + i;
    // theta = s * 10000^(-i/64) = s * 2^(-i*log2(1e4)/64)
    float th = (float)s * exp2f(-(float)i * 0.20762050593045952f);
    float cs = cosf(th), sn = sinf(th);
    float x1 = bf2f(x[base]), x2 = bf2f(x[base + 64]);
    x[base]      = f2bf(x1 * cs - x2 * sn);
    x[base + 64] = f2bf(x2 * cs + x1 * sn);
}

// ---------- causal flash attention -----------------------------------------
// grid (8, NH, B); 256 thr = 4 waves; KVBLK = 64, double-buffered LDS.
// LOAD BALANCE: causal work is triangular, so each block processes a
// complementary pair of 128-row q-tiles (phase 0: qt=8+p, phase 1: qt=7-p)
// -> every block does exactly 34 64-key steps; 512 uniform blocks = 2/CU.
__global__ __launch_bounds__(256) void flash_attn(
    const u16* __restrict__ qb, const u16* __restrict__ kb,
    const u16* __restrict__ vt, u16* __restrict__ ob)
{
    __shared__ __align__(16) u16 Ks[2][64 * 128];   // 2 x 16 KiB
    __shared__ __align__(16) u16 Vs[2][128 * 64];   // 2 x 16 KiB
    const int t    = threadIdx.x;
    const int lane = t & 63;
    const int w    = t >> 6;
    const int col  = lane & 15;
    const int g    = lane >> 4;
    const int p    = blockIdx.x;          // pair id 0..7
    const int qh   = blockIdx.y;
    const int b    = blockIdx.z;
    const int kvh  = qh >> 2;             // G = 4

    const u16* kbase = kb + ((size_t)b * 2048) * 1024 + kvh * 128;
    const u16* vbase = vt + ((size_t)kvh * 128) * 4096 + (size_t)b * 2048;

    // ---- staging constants (per-thread, phase-invariant) ----
    const int ksw = ((t >> 4) & 3) ^ (((t >> 4) & 8) >> 1);
    const u16* ksrc0 = kbase + (size_t)(t >> 4) * 1024 + (size_t)((t & 15) ^ ksw) * 8;
    const u16* vsrc0 = vbase + (size_t)(t >> 3) * 4096 + (size_t)(((t & 7) ^ ((t >> 3) & 7)) * 8);
    u16* kdst = &Ks[0][0] + t * 8;
    u16* vdst = &Vs[0][0] + t * 8;

    // ---- read constants ----
    const int swr = (col & 3) ^ (((col >> 2) & 1) << 2);
    int kb_[2][2];
#pragma unroll
    for (int h = 0; h < 2; h++)
#pragma unroll
        for (int kk = 0; kk < 2; kk++)
            kb_[h][kk] = (h * 32 + (col >> 2) * 8 + kk * 4 + (col & 3)) * 16;
    int cco[4];
#pragma unroll
    for (int c = 0; c < 4; c++) cco[c] = (c * 4 + g) ^ swr;
    const int vrow = col * 8;
    const int vcc0 = (g) ^ (col & 7);
    const int vcc1 = (4 + g) ^ (col & 7);

    const float SCL = 0.08838834764831845f * 1.4426950408889634f; // 1/sqrt(128)*log2(e)

    auto STAGE = [&](int bufi, int k0i) {
#pragma unroll
        for (int i = 0; i < 4; i++)
            gld16(ksrc0 + (size_t)k0i * 1024 + (size_t)i * 16384, kdst + bufi * 8192 + i * 2048);
#pragma unroll
        for (int i = 0; i < 4; i++)
            gld16(vsrc0 + (size_t)i * 131072 + k0i, vdst + bufi * 8192 + i * 2048);
    };

#pragma unroll 1
    for (int phase = 0; phase < 2; phase++) {
        const int qt = phase ? (7 - p) : (8 + p);
        const int Q0 = qt * 128;
        const int qw = Q0 + w * 32;

        // Q fragments (B-operand): Q[q][c*32 + g*8 + j]
        short8 qf[2][4];
#pragma unroll
        for (int sub = 0; sub < 2; sub++) {
            const u16* qrow = qb + ((size_t)(b * 2048 + qw + sub * 16 + col)) * 4096 + qh * 128;
#pragma unroll
            for (int c = 0; c < 4; c++)
                qf[sub][c] = *(const short8*)(qrow + c * 32 + g * 8);
        }

        float m_run[2] = {0.f, 0.f};   // log2-domain running max (deferred)
        float l_run[2] = {0.f, 0.f};
        f32x4 ot[2][8] = {};

        const int nsteps = (Q0 + 128) >> 6;
        const int qmax_w = qw + 31;

        int buf = 0;
        STAGE(0, 0);
        __syncthreads();

        for (int step = 0; step < nsteps; step++) {
            const int k0 = step << 6;
            if (step + 1 < nsteps) STAGE(buf ^ 1, k0 + 64);   // prefetch overlaps compute

            if (k0 <= qmax_w) {
                const u16* Kp = &Ks[buf][0];
                const u16* Vp = &Vs[buf][0];

                // scores: 32 MFMAs
                f32x4 sc[2][2][2] = {};   // [sub][h][kk]
                __builtin_amdgcn_s_setprio(1);
#pragma unroll
                for (int h = 0; h < 2; h++)
#pragma unroll
                    for (int c = 0; c < 4; c++)
#pragma unroll
                        for (int kk = 0; kk < 2; kk++) {
                            short8 kf = *(const short8*)(Kp + (size_t)(kb_[h][kk] + cco[c]) * 8);
                            sc[0][h][kk] = __builtin_amdgcn_mfma_f32_16x16x32_bf16(kf, qf[0][c], sc[0][h][kk], 0, 0, 0);
                            sc[1][h][kk] = __builtin_amdgcn_mfma_f32_16x16x32_bf16(kf, qf[1][c], sc[1][h][kk], 0, 0, 0);
                        }
                __builtin_amdgcn_s_setprio(0);

                const bool full = (k0 + 63 <= qw);   // wave-uniform
                short8 pf[2][2];
#pragma unroll
                for (int sub = 0; sub < 2; sub++) {
                    float s[16];
                    float tmax = -1e30f;
                    if (full) {
#pragma unroll
                        for (int h = 0; h < 2; h++)
#pragma unroll
                            for (int kk = 0; kk < 2; kk++)
#pragma unroll
                                for (int rr = 0; rr < 4; rr++) {
                                    float v = sc[sub][h][kk][rr] * SCL;
                                    s[h * 8 + kk * 4 + rr] = v;
                                    tmax = fmaxf(tmax, v);
                                }
                    } else {
                        const int q = qw + sub * 16 + col;
#pragma unroll
                        for (int h = 0; h < 2; h++)
#pragma unroll
                            for (int kk = 0; kk < 2; kk++)
#pragma unroll
                                for (int rr = 0; rr < 4; rr++) {
                                    int key = k0 + h * 32 + g * 8 + kk * 4 + rr;
                                    float v = sc[sub][h][kk][rr] * SCL;
                                    v = (key <= q) ? v : -1e30f;
                                    s[h * 8 + kk * 4 + rr] = v;
                                    tmax = fmaxf(tmax, v);
                                }
                    }
                    tmax = fmaxf(tmax, __shfl_xor(tmax, 16));
                    tmax = fmaxf(tmax, __shfl_xor(tmax, 32));
                    if (__any(tmax > m_run[sub] + 8.0f)) {
                        float m_new = fmaxf(m_run[sub], tmax);
                        float alpha = exp2_hw(m_run[sub] - m_new);
                        l_run[sub] *= alpha;
                        m_run[sub] = m_new;
#pragma unroll
                        for (int dt = 0; dt < 8; dt++)
#pragma unroll
                            for (int rr = 0; rr < 4; rr++) ot[sub][dt][rr] *= alpha;
                    }
                    const float m = m_run[sub];
                    float tsum = 0.f;
#pragma unroll
                    for (int j = 0; j < 16; j++) {
                        s[j] = exp2_hw(s[j] - m);   // masked lanes: 2^(-huge) -> 0
                        tsum += s[j];
                    }
#pragma unroll
                    for (int h = 0; h < 2; h++)
#pragma unroll
                        for (int jw = 0; jw < 4; jw++)
                            ((u32*)&pf[sub][h])[jw] = cvtpk_bf16(s[h * 8 + jw * 2], s[h * 8 + jw * 2 + 1]);
                    tsum += __shfl_xor(tsum, 16);
                    tsum += __shfl_xor(tsum, 32);
                    l_run[sub] += tsum;
                }

                // PV: 32 MFMAs, O^T += V^T * P^T
                __builtin_amdgcn_s_setprio(1);
#pragma unroll
                for (int dt = 0; dt < 8; dt++) {
                    short8 vf0 = *(const short8*)(Vp + (size_t)(dt * 128 + vrow + vcc0) * 8);
                    short8 vf1 = *(const short8*)(Vp + (size_t)(dt * 128 + vrow + vcc1) * 8);
                    ot[0][dt] = __builtin_amdgcn_mfma_f32_16x16x32_bf16(vf0, pf[0][0], ot[0][dt], 0, 0, 0);
                    ot[1][dt] = __builtin_amdgcn_mfma_f32_16x16x32_bf16(vf0, pf[1][0], ot[1][dt], 0, 0, 0);
                    ot[0][dt] = __builtin_amdgcn_mfma_f32_16x16x32_bf16(vf1, pf[0][1], ot[0][dt], 0, 0, 0);
                    ot[1][dt] = __builtin_amdgcn_mfma_f32_16x16x32_bf16(vf1, pf[1][1], ot[1][dt], 0, 0, 0);
                }
                __builtin_amdgcn_s_setprio(0);
            }
            __syncthreads();   // drains prefetch (vmcnt 0) + guards buffer reuse
            buf ^= 1;
        }

        // epilogue: O^T C-layout: dim = dt*16 + g*4 + rr, query = col
#pragma unroll
        for (int sub = 0; sub < 2; sub++) {
            float inv = 1.0f / l_run[sub];
            u16* orow = ob + ((size_t)(b * 2048 + qw + sub * 16 + col)) * 4096 + qh * 128;
#pragma unroll
            for (int dt = 0; dt < 8; dt++) {
                ushort4_t o;
#pragma unroll
                for (int rr = 0; rr < 4; rr++) o[rr] = f2bf(ot[sub][dt][rr] * inv);
                *(ushort4_t*)(orow + dt * 16 + g * 4) = o;
            }
        }
    }
}

// ---------------------------------------------------------------------------
extern "C" void kernel_launch(void* const* d_in, const int* in_sizes, int n_in,
                              void* d_out, int out_size, void* d_ws, size_t ws_size,
                              hipStream_t stream) {
    const float* hs = (const float*)d_in[0];  // [2,2048,4096]
    const float* Wq = (const float*)d_in[1];  // [4096,4096]
    const float* Wk = (const float*)d_in[2];  // [1024,4096]
    const float* Wv = (const float*)d_in[3];  // [1024,4096]
    const float* Wo = (const float*)d_in[4];  // [4096,4096]
    float* out = (float*)d_out;               // [2,2048,4096]

    char* ws = (char*)d_ws;
    u16* hsb = (u16*)(ws + 0);           // [4096,4096] bf16
    u16* Wqb = (u16*)(ws + 33554432);
    u16* Wkb = (u16*)(ws + 67108864);
    u16* Wvb = (u16*)(ws + 75497472);
    u16* Wob = (u16*)(ws + 83886080);
    u16* qb  = (u16*)(ws + 117440512);   // [4096,4096] bf16
    u16* kbf = (u16*)(ws + 150994944);   // [4096,1024] bf16
    u16* vtb = (u16*)(ws + 159383552);   // [1024,4096] bf16 (V transposed)
    u16* ab  = hsb;                      // alias: hs dead after QKV GEMMs

    cvt_f32_bf16<<<16384, 256, 0, stream>>>(hs, hsb, 4194304);
    cvt_f32_bf16<<<16384, 256, 0, stream>>>(Wq, Wqb, 4194304);
    cvt_f32_bf16<<<4096,  256, 0, stream>>>(Wk, Wkb, 1048576);
    cvt_f32_bf16<<<4096,  256, 0, stream>>>(Wv, Wvb, 1048576);
    cvt_f32_bf16<<<16384, 256, 0, stream>>>(Wo, Wob, 4194304);

    gemm_bt256<0><<<dim3(16, 16), 512, 0, stream>>>(hsb, Wqb, qb,  nullptr, 4096, 4096, 4096);
    gemm_bt<0><<<dim3(8, 32),  256, 0, stream>>>(hsb, Wkb, kbf, nullptr, 4096, 1024, 4096);
    gemm_bt<3><<<dim3(8, 32),  256, 0, stream>>>(hsb, Wvb, vtb, nullptr, 4096, 1024, 4096);

    rope_k<<<32768, 256, 0, stream>>>(qb,  11);
    rope_k<<<8192,  256, 0, stream>>>(kbf, 9);

    flash_attn<<<dim3(8, 32, 2), 256, 0, stream>>>(qb, kbf, vtb, ab);

    gemm_bt256<1><<<dim3(16, 16), 512, 0, stream>>>(ab, Wob, nullptr, out, 4096, 4096, 4096);
}

// Round 4
// 782.354 us; speedup vs baseline: 1.5031x; 1.0808x over previous
//
#include <hip/hip_runtime.h>

typedef unsigned short u16;
typedef unsigned int u32;
typedef __attribute__((ext_vector_type(8))) short short8;
typedef __attribute__((ext_vector_type(4))) float f32x4;
typedef __attribute__((ext_vector_type(4))) u16 ushort4_t;

// ---------- scalar conversion helpers --------------------------------------
__device__ __forceinline__ float bf2f(u16 u) {
    u32 x = ((u32)u) << 16;
    return __uint_as_float(x);
}
__device__ __forceinline__ u16 f2bf(float f) {  // round-to-nearest-even
    u32 x = __float_as_uint(f);
    x += 0x7FFFu + ((x >> 16) & 1u);
    return (u16)(x >> 16);
}
// packed f32x2 -> bf16x2 (RNE), gfx950 HW instruction
__device__ __forceinline__ u32 cvtpk_bf16(float lo, float hi) {
    u32 r;
    asm("v_cvt_pk_bf16_f32 %0, %1, %2" : "=v"(r) : "v"(lo), "v"(hi));
    return r;
}
// 2^x via HW transcendental (no libm guard code)
__device__ __forceinline__ float exp2_hw(float x) {
    float r;
    asm("v_exp_f32 %0, %1" : "=v"(r) : "v"(x));
    return r;
}

// ---------- async global->LDS (16B per lane, wave-uniform base) ------------
using as1_cv = __attribute__((address_space(1))) const void;
using as3_v  = __attribute__((address_space(3))) void;
__device__ __forceinline__ void gld16(const void* g, void* l) {
    __builtin_amdgcn_global_load_lds((as1_cv*)g, (as3_v*)l, 16, 0, 0);
}

// ---------- fp32 -> bf16 convert (4 elems/thread) --------------------------
__global__ void cvt_f32_bf16(const float* __restrict__ in, u16* __restrict__ out, int n4) {
    int i = blockIdx.x * 256 + threadIdx.x;
    if (i >= n4) return;
    float4 v = ((const float4*)in)[i];
    ushort4_t o;
    o[0] = f2bf(v.x); o[1] = f2bf(v.y); o[2] = f2bf(v.z); o[3] = f2bf(v.w);
    ((ushort4_t*)out)[i] = o;
}

// ---------- GEMM (128x128 tile): C[M,N] = A[M,K] * B[N,K]^T ----------------
// OUT_MODE: 0 = bf16 out, 1 = f32 out, 3 = bf16 TRANSPOSED out (Ct[N,M])
template <int OUT_MODE>
__global__ __launch_bounds__(256) void gemm_bt(
    const u16* __restrict__ A, const u16* __restrict__ B,
    u16* __restrict__ Cb, float* __restrict__ Cf,
    int M, int N, int K)
{
    __shared__ __align__(16) u16 As[128 * 32];
    __shared__ __align__(16) u16 Bs[128 * 32];
    const int t    = threadIdx.x;
    const int lane = t & 63;
    const int w    = t >> 6;
    const int wm   = w & 1;
    const int wn   = w >> 1;
    const int bx   = blockIdx.x;   // N tile
    const int by   = blockIdx.y;   // M tile

    const int r  = t >> 2;
    const int c8 = (t & 3) * 8;
    const u16* gA0 = A + (size_t)(by * 128 + r) * K + c8;
    const u16* gA1 = gA0 + (size_t)64 * K;
    const u16* gB0 = B + (size_t)(bx * 128 + r) * K + c8;
    const u16* gB1 = gB0 + (size_t)64 * K;
    u16* lA0 = &As[t * 8];
    u16* lA1 = &As[2048 + t * 8];
    u16* lB0 = &Bs[t * 8];
    u16* lB1 = &Bs[2048 + t * 8];

    f32x4 acc[4][4] = {};

    const int arow = wm * 64 + (lane & 15);
    const int brow = wn * 64 + (lane & 15);
    const int koff = (lane >> 4) * 8;

    for (int kt = 0; kt < K; kt += 32) {
        gld16(gA0 + kt, lA0);
        gld16(gA1 + kt, lA1);
        gld16(gB0 + kt, lB0);
        gld16(gB1 + kt, lB1);
        __syncthreads();
        short8 af[4], bf[4];
#pragma unroll
        for (int i = 0; i < 4; i++)
            af[i] = *(const short8*)&As[(arow + i * 16) * 32 + koff];
#pragma unroll
        for (int i = 0; i < 4; i++)
            bf[i] = *(const short8*)&Bs[(brow + i * 16) * 32 + koff];
#pragma unroll
        for (int mi = 0; mi < 4; mi++)
#pragma unroll
            for (int ni = 0; ni < 4; ni++)
                acc[mi][ni] = __builtin_amdgcn_mfma_f32_16x16x32_bf16(
                    af[mi], bf[ni], acc[mi][ni], 0, 0, 0);
        __syncthreads();
    }

    const int row0 = by * 128 + wm * 64 + (lane >> 4) * 4;
    const int col0 = bx * 128 + wn * 64 + (lane & 15);
#pragma unroll
    for (int mi = 0; mi < 4; mi++) {
#pragma unroll
        for (int ni = 0; ni < 4; ni++) {
            if (OUT_MODE == 3) {
                // transposed bf16: Ct[col][row], 4 consecutive rows -> 8B store
                ushort4_t o;
#pragma unroll
                for (int rr = 0; rr < 4; rr++) o[rr] = f2bf(acc[mi][ni][rr]);
                int col = col0 + ni * 16;
                *(ushort4_t*)&Cb[(size_t)col * M + row0 + mi * 16] = o;
            } else {
#pragma unroll
                for (int rr = 0; rr < 4; rr++) {
                    int row = row0 + mi * 16 + rr;
                    int col = col0 + ni * 16;
                    float v = acc[mi][ni][rr];
                    if (OUT_MODE == 1) Cf[(size_t)row * N + col] = v;
                    else               Cb[(size_t)row * N + col] = f2bf(v);
                }
            }
        }
    }
}

// ---------- GEMM (256x256 tile, BK=32, ring-4 LDS, counted vmcnt) ----------
template <int OUT_MODE>   // 0 = bf16 out, 1 = f32 out
__global__ __launch_bounds__(512, 2) void gemm_bt256(
    const u16* __restrict__ A, const u16* __restrict__ B,
    u16* __restrict__ Cb, float* __restrict__ Cf,
    int M, int N, int K)
{
    __shared__ __align__(16) u16 S[65536];   // 4 slots x 16384 u16 (A: +0, B: +8192)
    const int t    = threadIdx.x;
    const int lane = t & 63;
    const int w    = t >> 6;
    const int wm   = w >> 2;        // 0..1
    const int wn   = w & 3;         // 0..3
    const int col  = lane & 15;
    const int g    = lane >> 4;

    // staging source: thread t stages rows (t>>2) and (t>>2)+128;
    // source k-chunk carries the inverse swizzle: kel = ((t&3)^((t>>4)&3))*8
    const int kel = (((t & 3) ^ ((t >> 4) & 3)) * 8);
    const u16* gA = A + (size_t)(blockIdx.y * 256 + (t >> 2)) * K + kel;
    const u16* gB = B + (size_t)(blockIdx.x * 256 + (t >> 2)) * K + kel;
    const size_t rstride = (size_t)128 * K;
    u16* ldsA = &S[t * 8];
    u16* ldsB = &S[8192 + t * 8];

    // read offset within a subtile (u16 units): swizzled chunk * 8
    const int rchunk = (((col * 4 + g) ^ ((col >> 2) & 3)) * 8);
    int aoff[8], boff[4];
#pragma unroll
    for (int mi = 0; mi < 8; mi++) aoff[mi] = (wm * 8 + mi) * 512 + rchunk;
#pragma unroll
    for (int ni = 0; ni < 4; ni++) boff[ni] = 8192 + (wn * 4 + ni) * 512 + rchunk;

    f32x4 acc[8][4] = {};

    auto STAGE = [&](int slot, int kt) {
        const size_t so = (size_t)slot * 16384;
        gld16(gA + kt,            ldsA + so);
        gld16(gA + kt + rstride,  ldsA + so + 4096);
        gld16(gB + kt,            ldsB + so);
        gld16(gB + kt + rstride,  ldsB + so + 4096);
    };

    const int NT = K >> 5;   // 128 K-tiles of 32
    STAGE(0, 0);
    STAGE(1, 32);
    STAGE(2, 64);

    for (int kt = 0; kt < NT; kt++) {
        // counted wait: tile kt complete; kt+1/kt+2 (4 loads each) in flight
        if (kt < NT - 2)      asm volatile("s_waitcnt vmcnt(8)" ::: "memory");
        else if (kt < NT - 1) asm volatile("s_waitcnt vmcnt(4)" ::: "memory");
        else                  asm volatile("s_waitcnt vmcnt(0)" ::: "memory");
        __builtin_amdgcn_s_barrier();
        asm volatile("" ::: "memory");
        if (kt < NT - 3) STAGE((kt + 3) & 3, (kt + 3) << 5);

        const u16* Sb = &S[(kt & 3) * 16384];
        short8 af[8], bf[4];
#pragma unroll
        for (int mi = 0; mi < 8; mi++) af[mi] = *(const short8*)(Sb + aoff[mi]);
#pragma unroll
        for (int ni = 0; ni < 4; ni++) bf[ni] = *(const short8*)(Sb + boff[ni]);

        __builtin_amdgcn_s_setprio(1);
#pragma unroll
        for (int mi = 0; mi < 8; mi++)
#pragma unroll
            for (int ni = 0; ni < 4; ni++)
                acc[mi][ni] = __builtin_amdgcn_mfma_f32_16x16x32_bf16(
                    af[mi], bf[ni], acc[mi][ni], 0, 0, 0);
        __builtin_amdgcn_s_setprio(0);
    }

    const int row0 = blockIdx.y * 256 + wm * 128 + (lane >> 4) * 4;
    const int col0 = blockIdx.x * 256 + wn * 64 + (lane & 15);
#pragma unroll
    for (int mi = 0; mi < 8; mi++) {
#pragma unroll
        for (int ni = 0; ni < 4; ni++) {
#pragma unroll
            for (int rr = 0; rr < 4; rr++) {
                int row = row0 + mi * 16 + rr;
                int col = col0 + ni * 16;
                float v = acc[mi][ni][rr];
                if (OUT_MODE == 1) Cf[(size_t)row * N + col] = v;
                else               Cb[(size_t)row * N + col] = f2bf(v);
            }
        }
    }
}

// ---------- RoPE in-place on bf16 [B*S, H*128], optional output scale ------
__global__ void rope_k(u16* __restrict__ x, int hshift, float scale) {
    int idx = blockIdx.x * 256 + threadIdx.x;
    int i   = idx & 63;
    int hm  = (1 << (hshift - 6)) - 1;
    int h   = (idx >> 6) & hm;
    int row = idx >> hshift;       // 0..B*S-1
    int s   = row & 2047;          // position within sequence
    int stride = (hm + 1) * 128;
    size_t base = (size_t)row * stride + h * 128 + i;
    // theta = s * 10000^(-i/64) = s * 2^(-i*log2(1e4)/64)
    float th = (float)s * exp2f(-(float)i * 0.20762050593045952f);
    float cs = cosf(th), sn = sinf(th);
    float x1 = bf2f(x[base]), x2 = bf2f(x[base + 64]);
    x[base]      = f2bf((x1 * cs - x2 * sn) * scale);
    x[base + 64] = f2bf((x2 * cs + x1 * sn) * scale);
}

// ---------- causal flash attention -----------------------------------------
// grid (4, NH, B); 512 thr = 8 waves; 256 q rows/block (32/wave, 2 subtiles);
// KVBLK = 64; ring-3 LDS (96 KiB -> 1 block/CU, 8 waves = 2/SIMD).
// Schedule per 64-key step (gemm_bt256-style counted pipeline):
//   s_waitcnt vmcnt(4)  [vmcnt(0) only on final step]  -> s_barrier ->
//   stage step+2 -> compute step.  Two tiles always in flight; no full
//   vmcnt(0) drain in steady state (T4).  Reads of slot s all retire (lgkm
//   before MFMA) before the barrier preceding the stage of s+3.
// LOAD BALANCE: pair p handles qt=4+p then qt=3-p (256-row tiles):
//   (20+4p) + (16-4p) = 36 steps for every block; 256 uniform blocks = 1/CU.
// Q is PRE-SCALED by 1/sqrt(128)*log2(e) in rope_k -> no per-score mul here.
// scores: S^T = Kperm * Q^T (A rows permuted: key(m)=(m>>2)*8+kk*4+(m&3));
// PV: O^T += V^T * P^T, V^T staged [dim][64key], XOR swizzle cc^=(dim&7).
__global__ __launch_bounds__(512) void flash_attn(
    const u16* __restrict__ qb, const u16* __restrict__ kb,
    const u16* __restrict__ vt, u16* __restrict__ ob)
{
    __shared__ __align__(16) u16 Ks[3][64 * 128];   // 3 x 16 KiB
    __shared__ __align__(16) u16 Vs[3][128 * 64];   // 3 x 16 KiB
    const int t    = threadIdx.x;
    const int lane = t & 63;
    const int w    = t >> 6;          // 0..7
    const int col  = lane & 15;
    const int g    = lane >> 4;
    const int p    = blockIdx.x;      // pair id 0..3
    const int qh   = blockIdx.y;
    const int b    = blockIdx.z;
    const int kvh  = qh >> 2;         // G = 4

    const u16* kbase = kb + ((size_t)b * 2048) * 1024 + kvh * 128;
    const u16* vbase = vt + ((size_t)kvh * 128) * 4096 + (size_t)b * 2048;

    // ---- staging constants (512 threads) ----
    // K issue i (i=0,1): thread t stages key (t>>4)+i*32, chunk (t&15)^sw(key);
    //   sw(key)=(key&3)^((key&8)>>1); +32 leaves key bits {0,1,3} unchanged.
    const int ksw = ((t >> 4) & 3) ^ (((t >> 4) & 8) >> 1);
    const u16* ksrc0 = kbase + (size_t)(t >> 4) * 1024 + (size_t)((t & 15) ^ ksw) * 8;
    // V issue i: thread t stages dim (t>>3)+i*64, LDS chunk cc=t&7 holding
    //   source key-chunk cc^(dim&7); +64 leaves dim&7 unchanged.
    const u16* vsrc0 = vbase + (size_t)(t >> 3) * 4096 + (size_t)(((t & 7) ^ ((t >> 3) & 7)) * 8);
    u16* kdst = &Ks[0][0] + t * 8;
    u16* vdst = &Vs[0][0] + t * 8;

    // ---- read constants ----
    const int swr = (col & 3) ^ (((col >> 2) & 1) << 2);
    int kb_[2][2];
#pragma unroll
    for (int h = 0; h < 2; h++)
#pragma unroll
        for (int kk = 0; kk < 2; kk++)
            kb_[h][kk] = (h * 32 + (col >> 2) * 8 + kk * 4 + (col & 3)) * 16;
    int cco[4];
#pragma unroll
    for (int c = 0; c < 4; c++) cco[c] = (c * 4 + g) ^ swr;
    const int vrow = col * 8;
    const int vcc0 = (g) ^ (col & 7);
    const int vcc1 = (4 + g) ^ (col & 7);

    auto STAGE = [&](int slot, int k0i) {
        const size_t so = (size_t)slot * 8192;
        gld16(ksrc0 + (size_t)k0i * 1024,        kdst + so);
        gld16(ksrc0 + (size_t)(k0i + 32) * 1024, kdst + so + 4096);
        gld16(vsrc0 + k0i,                       vdst + so);
        gld16(vsrc0 + (size_t)64 * 4096 + k0i,   vdst + so + 4096);
    };

#pragma unroll 1
    for (int phase = 0; phase < 2; phase++) {
        const int qt = phase ? (3 - p) : (4 + p);
        const int Q0 = qt * 256;
        const int qw = Q0 + w * 32;

        // Q fragments (B-operand): Q[q][c*32 + g*8 + j] (pre-scaled by rope)
        short8 qf[2][4];
#pragma unroll
        for (int sub = 0; sub < 2; sub++) {
            const u16* qrow = qb + ((size_t)(b * 2048 + qw + sub * 16 + col)) * 4096 + qh * 128;
#pragma unroll
            for (int c = 0; c < 4; c++)
                qf[sub][c] = *(const short8*)(qrow + c * 32 + g * 8);
        }

        float m_run[2] = {0.f, 0.f};   // log2-domain running max (deferred)
        float l_run[2] = {0.f, 0.f};
        f32x4 ot[2][8] = {};

        const int nsteps = (Q0 + 256) >> 6;   // >= 4 always
        const int qmax_w = qw + 31;

        STAGE(0, 0);
        STAGE(1, 64);
        int slc = 0;   // compute slot (ring-3)

        for (int step = 0; step < nsteps; step++) {
            const int k0 = step << 6;
            if (step + 1 < nsteps) asm volatile("s_waitcnt vmcnt(4)" ::: "memory");
            else                   asm volatile("s_waitcnt vmcnt(0)" ::: "memory");
            __builtin_amdgcn_s_barrier();
            asm volatile("" ::: "memory");
            if (step + 2 < nsteps) {
                int sl2 = slc + 2; if (sl2 >= 3) sl2 -= 3;
                STAGE(sl2, (step + 2) << 6);
            }

            if (k0 <= qmax_w) {
                const u16* Kp = &Ks[slc][0];
                const u16* Vp = &Vs[slc][0];

                // scores: 32 MFMAs
                f32x4 sc[2][2][2] = {};   // [sub][h][kk]
                __builtin_amdgcn_s_setprio(1);
#pragma unroll
                for (int h = 0; h < 2; h++)
#pragma unroll
                    for (int c = 0; c < 4; c++)
#pragma unroll
                        for (int kk = 0; kk < 2; kk++) {
                            short8 kf = *(const short8*)(Kp + (size_t)(kb_[h][kk] + cco[c]) * 8);
                            sc[0][h][kk] = __builtin_amdgcn_mfma_f32_16x16x32_bf16(kf, qf[0][c], sc[0][h][kk], 0, 0, 0);
                            sc[1][h][kk] = __builtin_amdgcn_mfma_f32_16x16x32_bf16(kf, qf[1][c], sc[1][h][kk], 0, 0, 0);
                        }
                __builtin_amdgcn_s_setprio(0);

                const bool full = (k0 + 63 <= qw);   // wave-uniform
                short8 pf[2][2];
#pragma unroll
                for (int sub = 0; sub < 2; sub++) {
                    float s[16];
                    float tmax = -1e30f;
                    if (full) {
#pragma unroll
                        for (int h = 0; h < 2; h++)
#pragma unroll
                            for (int kk = 0; kk < 2; kk++)
#pragma unroll
                                for (int rr = 0; rr < 4; rr++) {
                                    float v = sc[sub][h][kk][rr];
                                    s[h * 8 + kk * 4 + rr] = v;
                                    tmax = fmaxf(tmax, v);
                                }
                    } else {
                        const int q = qw + sub * 16 + col;
#pragma unroll
                        for (int h = 0; h < 2; h++)
#pragma unroll
                            for (int kk = 0; kk < 2; kk++)
#pragma unroll
                                for (int rr = 0; rr < 4; rr++) {
                                    int key = k0 + h * 32 + g * 8 + kk * 4 + rr;
                                    float v = sc[sub][h][kk][rr];
                                    v = (key <= q) ? v : -1e30f;
                                    s[h * 8 + kk * 4 + rr] = v;
                                    tmax = fmaxf(tmax, v);
                                }
                    }
                    tmax = fmaxf(tmax, __shfl_xor(tmax, 16));
                    tmax = fmaxf(tmax, __shfl_xor(tmax, 32));
                    if (__any(tmax > m_run[sub] + 8.0f)) {
                        float m_new = fmaxf(m_run[sub], tmax);
                        float alpha = exp2_hw(m_run[sub] - m_new);
                        l_run[sub] *= alpha;
                        m_run[sub] = m_new;
#pragma unroll
                        for (int dt = 0; dt < 8; dt++)
#pragma unroll
                            for (int rr = 0; rr < 4; rr++) ot[sub][dt][rr] *= alpha;
                    }
                    const float m = m_run[sub];
                    float tsum = 0.f;
#pragma unroll
                    for (int j = 0; j < 16; j++) {
                        s[j] = exp2_hw(s[j] - m);   // masked lanes: 2^(-huge) -> 0
                        tsum += s[j];
                    }
#pragma unroll
                    for (int h = 0; h < 2; h++)
#pragma unroll
                        for (int jw = 0; jw < 4; jw++)
                            ((u32*)&pf[sub][h])[jw] = cvtpk_bf16(s[h * 8 + jw * 2], s[h * 8 + jw * 2 + 1]);
                    tsum += __shfl_xor(tsum, 16);
                    tsum += __shfl_xor(tsum, 32);
                    l_run[sub] += tsum;
                }

                // PV: 32 MFMAs, O^T += V^T * P^T
                __builtin_amdgcn_s_setprio(1);
#pragma unroll
                for (int dt = 0; dt < 8; dt++) {
                    short8 vf0 = *(const short8*)(Vp + (size_t)(dt * 128 + vrow + vcc0) * 8);
                    short8 vf1 = *(const short8*)(Vp + (size_t)(dt * 128 + vrow + vcc1) * 8);
                    ot[0][dt] = __builtin_amdgcn_mfma_f32_16x16x32_bf16(vf0, pf[0][0], ot[0][dt], 0, 0, 0);
                    ot[1][dt] = __builtin_amdgcn_mfma_f32_16x16x32_bf16(vf0, pf[1][0], ot[1][dt], 0, 0, 0);
                    ot[0][dt] = __builtin_amdgcn_mfma_f32_16x16x32_bf16(vf1, pf[0][1], ot[0][dt], 0, 0, 0);
                    ot[1][dt] = __builtin_amdgcn_mfma_f32_16x16x32_bf16(vf1, pf[1][1], ot[1][dt], 0, 0, 0);
                }
                __builtin_amdgcn_s_setprio(0);
            }
            slc = (slc == 2) ? 0 : slc + 1;
        }
        // all waves must finish reading LDS before next phase's prologue
        // overwrites slot 0 (epilogue below touches no LDS)
        __syncthreads();

        // epilogue: O^T C-layout: dim = dt*16 + g*4 + rr, query = col
#pragma unroll
        for (int sub = 0; sub < 2; sub++) {
            float inv = 1.0f / l_run[sub];
            u16* orow = ob + ((size_t)(b * 2048 + qw + sub * 16 + col)) * 4096 + qh * 128;
#pragma unroll
            for (int dt = 0; dt < 8; dt++) {
                ushort4_t o;
#pragma unroll
                for (int rr = 0; rr < 4; rr++) o[rr] = f2bf(ot[sub][dt][rr] * inv);
                *(ushort4_t*)(orow + dt * 16 + g * 4) = o;
            }
        }
    }
}

// ---------------------------------------------------------------------------
extern "C" void kernel_launch(void* const* d_in, const int* in_sizes, int n_in,
                              void* d_out, int out_size, void* d_ws, size_t ws_size,
                              hipStream_t stream) {
    const float* hs = (const float*)d_in[0];  // [2,2048,4096]
    const float* Wq = (const float*)d_in[1];  // [4096,4096]
    const float* Wk = (const float*)d_in[2];  // [1024,4096]
    const float* Wv = (const float*)d_in[3];  // [1024,4096]
    const float* Wo = (const float*)d_in[4];  // [4096,4096]
    float* out = (float*)d_out;               // [2,2048,4096]

    char* ws = (char*)d_ws;
    u16* hsb = (u16*)(ws + 0);           // [4096,4096] bf16
    u16* Wqb = (u16*)(ws + 33554432);
    u16* Wkb = (u16*)(ws + 67108864);
    u16* Wvb = (u16*)(ws + 75497472);
    u16* Wob = (u16*)(ws + 83886080);
    u16* qb  = (u16*)(ws + 117440512);   // [4096,4096] bf16
    u16* kbf = (u16*)(ws + 150994944);   // [4096,1024] bf16
    u16* vtb = (u16*)(ws + 159383552);   // [1024,4096] bf16 (V transposed)
    u16* ab  = hsb;                      // alias: hs dead after QKV GEMMs

    cvt_f32_bf16<<<16384, 256, 0, stream>>>(hs, hsb, 4194304);
    cvt_f32_bf16<<<16384, 256, 0, stream>>>(Wq, Wqb, 4194304);
    cvt_f32_bf16<<<4096,  256, 0, stream>>>(Wk, Wkb, 1048576);
    cvt_f32_bf16<<<4096,  256, 0, stream>>>(Wv, Wvb, 1048576);
    cvt_f32_bf16<<<16384, 256, 0, stream>>>(Wo, Wob, 4194304);

    gemm_bt256<0><<<dim3(16, 16), 512, 0, stream>>>(hsb, Wqb, qb,  nullptr, 4096, 4096, 4096);
    gemm_bt<0><<<dim3(8, 32),  256, 0, stream>>>(hsb, Wkb, kbf, nullptr, 4096, 1024, 4096);
    gemm_bt<3><<<dim3(8, 32),  256, 0, stream>>>(hsb, Wvb, vtb, nullptr, 4096, 1024, 4096);

    // Q pre-scaled by 1/sqrt(128)*log2(e): flash_attn scores are then
    // directly in the log2 softmax domain with no per-score multiply.
    rope_k<<<32768, 256, 0, stream>>>(qb,  11, 0.08838834764831845f * 1.4426950408889634f);
    rope_k<<<8192,  256, 0, stream>>>(kbf, 9, 1.0f);

    flash_attn<<<dim3(4, 32, 2), 512, 0, stream>>>(qb, kbf, vtb, ab);

    gemm_bt256<1><<<dim3(16, 16), 512, 0, stream>>>(ab, Wob, nullptr, out, 4096, 4096, 4096);
}